// Round 1
// baseline (330.687 us; speedup 1.0000x reference)
//
#include <hip/hip_runtime.h>
#include <math.h>

#define NB 128     // batch
#define NC 64      // channels
#define NT 128     // segment length
#define HIDN 128   // hidden
#define NE 64      // attn embed
#define NHD 4      // heads
#define HD 16      // head dim

// ---------------------------------------------------------------------------
// 1. Analytic signal (Hilbert with reference's mask: bins [0,64) * 2, rest 0)
//    analytic[t] = x[t] + (1/64) * sum_{d odd} x[(t-d)&127] * (1 + i*cot(pi*d/128))
//    Stored as re/im in [b][t][c] layout for coalesced PLI reads.
// ---------------------------------------------------------------------------
__global__ void analytic_kernel(const float* __restrict__ eeg,
                                float* __restrict__ re, float* __restrict__ im) {
    int row = blockIdx.x;            // b*NC + c
    int b = row >> 6, c = row & 63;
    int t = threadIdx.x;             // 0..127
    __shared__ float xs[NT];
    __shared__ double cotv[64];
    xs[t] = eeg[row * NT + t];
    if (t < 64) {
        double d = (double)(2 * t + 1);
        double a = 3.14159265358979323846 * d / 128.0;
        cotv[t] = cos(a) / sin(a);
    }
    __syncthreads();
    double ar = 0.0, ai = 0.0;
    #pragma unroll
    for (int m = 0; m < 64; ++m) {
        int d = 2 * m + 1;
        int s = (t - d) & 127;
        double xv = (double)xs[s];
        ar += xv;
        ai += cotv[m] * xv;
    }
    double rr = (double)xs[t] + ar * (1.0 / 64.0);
    double ii = ai * (1.0 / 64.0);
    re[b * (NT * NC) + t * NC + c] = (float)rr;
    im[b * (NT * NC) + t * NC + c] = (float)ii;
}

// ---------------------------------------------------------------------------
// 2. PLI: pli[b,i,j] = |mean_t sign(im_i*re_j - re_i*im_j)|, diag zeroed.
//    Also computes deg[b,i] = sum_j pli (row sums) via wave reduction.
//    Writes pli directly into d_out (wpli output region).
// ---------------------------------------------------------------------------
__global__ void pli_kernel(const float* __restrict__ re, const float* __restrict__ im,
                           float* __restrict__ wpli, float* __restrict__ deg) {
    int row = blockIdx.x;            // b*NC + i
    int b = row >> 6, i = row & 63;
    int j = threadIdx.x;             // 0..63
    const float* reb = re + b * (NT * NC);
    const float* imb = im + b * (NT * NC);
    int acc = 0;
    for (int t = 0; t < NT; ++t) {
        float ri = reb[t * NC + i];  // broadcast
        float ii = imb[t * NC + i];
        float rj = reb[t * NC + j];  // coalesced
        float ij = imb[t * NC + j];
        float cross = ii * rj - ri * ij;   // ~ sin(phi_i - phi_j) * |zi||zj|
        acc += (cross > 0.f) ? 1 : ((cross < 0.f) ? -1 : 0);
    }
    float p = fabsf((float)acc * (1.f / (float)NT));
    if (j == i) p = 0.f;
    wpli[b * (NC * NC) + i * NC + j] = p;
    float s = p;
    #pragma unroll
    for (int off = 32; off > 0; off >>= 1) s += __shfl_down(s, off);
    if (j == 0) deg[row] = s;
}

// ---------------------------------------------------------------------------
// 3. GCN support: out[b,i,f] = sum_j adj[b,i,j]*dn[i]*dn[j] * x[b,j,f]
// ---------------------------------------------------------------------------
__global__ void gcn_support_kernel(const float* __restrict__ adj,
                                   const float* __restrict__ deg,
                                   const float* __restrict__ x,
                                   float* __restrict__ out, int F) {
    int row = blockIdx.x;            // b*NC + i
    int b = row >> 6, i = row & 63;
    int f = threadIdx.x;             // 0..F-1
    __shared__ float dn[NC];
    __shared__ float arow[NC];
    if (f < NC) dn[f] = (float)(1.0 / sqrt((double)deg[b * NC + f] + 1e-8));
    __syncthreads();
    if (f < NC) arow[f] = adj[b * NC * NC + i * NC + f] * dn[i] * dn[f];
    __syncthreads();
    float acc = 0.f;
    #pragma unroll
    for (int jj = 0; jj < NC; ++jj)
        acc += arow[jj] * x[b * NC * F + jj * F + f];
    out[b * NC * F + i * F + f] = acc;
}

// ---------------------------------------------------------------------------
// 4. Row-wise linear: out[row,o] = sum_k in[row,k]*W[o,k] + bias[o]
// ---------------------------------------------------------------------------
template <int K, int OUT>
__global__ void linproj_kernel(const float* __restrict__ in, const float* __restrict__ W,
                               const float* __restrict__ bias, float* __restrict__ out) {
    int row = blockIdx.x;
    int o = threadIdx.x;             // 0..OUT-1
    __shared__ float s[K];
    for (int idx = threadIdx.x; idx < K; idx += OUT) s[idx] = in[row * K + idx];
    __syncthreads();
    float acc = bias[o];
    #pragma unroll
    for (int k = 0; k < K; ++k) acc += s[k] * W[o * K + k];
    out[row * OUT + o] = acc;
}

// ---------------------------------------------------------------------------
// 5. BN stats per channel over (B,F): mean and rstd (deterministic reduction)
// ---------------------------------------------------------------------------
__global__ void bn_stats_kernel(const float* __restrict__ x, int F,
                                float* __restrict__ mr) {
    int c = blockIdx.x;
    int tid = threadIdx.x;           // 256
    double s = 0.0, s2 = 0.0;
    int total = NB * F;
    for (int idx = tid; idx < total; idx += 256) {
        int b = idx / F, f = idx - b * F;
        float v = x[b * NC * F + c * F + f];
        s += (double)v;
        s2 += (double)v * (double)v;
    }
    __shared__ double ls[256], ls2[256];
    ls[tid] = s; ls2[tid] = s2;
    __syncthreads();
    for (int off = 128; off > 0; off >>= 1) {
        if (tid < off) { ls[tid] += ls[tid + off]; ls2[tid] += ls2[tid + off]; }
        __syncthreads();
    }
    if (tid == 0) {
        double N = (double)total;
        double m = ls[0] / N;
        double var = ls2[0] / N - m * m;
        mr[2 * c] = (float)m;
        mr[2 * c + 1] = (float)(1.0 / sqrt(var + 1e-5));
    }
}

// ---------------------------------------------------------------------------
// 6. BN apply + ReLU (in place)
// ---------------------------------------------------------------------------
__global__ void bn_apply_kernel(float* __restrict__ x, const float* __restrict__ mr,
                                const float* __restrict__ g, const float* __restrict__ bb,
                                int F, int total) {
    int idx = blockIdx.x * blockDim.x + threadIdx.x;
    if (idx >= total) return;
    int c = (idx / F) & (NC - 1);
    float v = (x[idx] - mr[2 * c]) * mr[2 * c + 1] * g[c] + bb[c];
    x[idx] = v > 0.f ? v : 0.f;
}

// ---------------------------------------------------------------------------
// 7. QKV projection per batch: qkv[b,n,o] = sum_d x[b,n,d]*W[o,d] + bias[o]
// ---------------------------------------------------------------------------
__global__ void qkv_kernel(const float* __restrict__ x, const float* __restrict__ W,
                           const float* __restrict__ bias, float* __restrict__ qkv) {
    int b = blockIdx.x;
    __shared__ float xs[NE * NE];
    for (int idx = threadIdx.x; idx < NE * NE; idx += 256) xs[idx] = x[b * 4096 + idx];
    __syncthreads();
    for (int idx = threadIdx.x; idx < NE * 3 * NE; idx += 256) {
        int n = idx / (3 * NE), o = idx - n * (3 * NE);
        float acc = bias[o];
        #pragma unroll
        for (int d = 0; d < NE; ++d) acc += xs[n * NE + d] * W[o * NE + d];
        qkv[b * (NE * 3 * NE) + idx] = acc;
    }
}

// ---------------------------------------------------------------------------
// 8. Attention per (b, head): thread = query row. scores->softmax->PV.
// ---------------------------------------------------------------------------
__global__ void attn_kernel(const float* __restrict__ qkv, float* __restrict__ ao) {
    int b = blockIdx.x >> 2, h = blockIdx.x & 3;
    int n = threadIdx.x;             // 0..63
    __shared__ float ks[NE][HD], vs[NE][HD];
    const float* base = qkv + b * (NE * 3 * NE);
    #pragma unroll
    for (int d = 0; d < HD; ++d) {
        ks[n][d] = base[n * 192 + 64 + h * HD + d];
        vs[n][d] = base[n * 192 + 128 + h * HD + d];
    }
    float q[HD];
    #pragma unroll
    for (int d = 0; d < HD; ++d) q[d] = base[n * 192 + h * HD + d];
    __syncthreads();
    float sc[NE];
    float mx = -1e30f;
    #pragma unroll
    for (int j = 0; j < NE; ++j) {
        float acc = 0.f;
        #pragma unroll
        for (int d = 0; d < HD; ++d) acc += q[d] * ks[j][d];
        acc *= 0.25f;                // 1/sqrt(16)
        sc[j] = acc;
        mx = fmaxf(mx, acc);
    }
    float sum = 0.f;
    #pragma unroll
    for (int j = 0; j < NE; ++j) { sc[j] = expf(sc[j] - mx); sum += sc[j]; }
    float inv = 1.f / sum;
    float o[HD];
    #pragma unroll
    for (int d = 0; d < HD; ++d) o[d] = 0.f;
    #pragma unroll
    for (int j = 0; j < NE; ++j) {
        float p = sc[j] * inv;
        #pragma unroll
        for (int d = 0; d < HD; ++d) o[d] += p * vs[j][d];
    }
    #pragma unroll
    for (int d = 0; d < HD; ++d) ao[b * 4096 + n * 64 + h * HD + d] = o[d];
}

// ---------------------------------------------------------------------------
// 9. Mean over nodes, then output projection: feat[b,e]=sum_d mean_o[d]*W[e,d]+b[e]
// ---------------------------------------------------------------------------
__global__ void outmean_kernel(const float* __restrict__ ao, const float* __restrict__ W,
                               const float* __restrict__ bias, float* __restrict__ feat) {
    int b = blockIdx.x;
    int tid = threadIdx.x;           // 0..63
    float s = 0.f;
    for (int n = 0; n < NE; ++n) s += ao[b * 4096 + n * 64 + tid];
    __shared__ float mo[NE];
    mo[tid] = s * (1.f / 64.f);
    __syncthreads();
    float acc = bias[tid];
    #pragma unroll
    for (int d = 0; d < NE; ++d) acc += mo[d] * W[tid * NE + d];
    feat[b * NE + tid] = acc;
}

// ---------------------------------------------------------------------------
extern "C" void kernel_launch(void* const* d_in, const int* in_sizes, int n_in,
                              void* d_out, int out_size, void* d_ws, size_t ws_size,
                              hipStream_t stream) {
    const float* eeg      = (const float*)d_in[0];
    const float* gcn1_w   = (const float*)d_in[1];
    const float* gcn1_b   = (const float*)d_in[2];
    const float* gcn2_w   = (const float*)d_in[3];
    const float* gcn2_b   = (const float*)d_in[4];
    const float* bn1_g    = (const float*)d_in[5];
    const float* bn1_b    = (const float*)d_in[6];
    const float* bn2_g    = (const float*)d_in[7];
    const float* bn2_b    = (const float*)d_in[8];
    const float* attn_in_w  = (const float*)d_in[9];
    const float* attn_in_b  = (const float*)d_in[10];
    const float* attn_out_w = (const float*)d_in[11];
    const float* attn_out_b = (const float*)d_in[12];

    float* out  = (float*)d_out;
    float* feat = out;               // [B, E] = 8192 floats
    float* wpli = out + NB * NE;     // [B, C, C] = 524288 floats

    float* ws = (float*)d_ws;
    // layout (floats): re[1M] im[1M] s1[1M] x1[1M] x2[512K] deg[8K] stats[256]
    float* w_re    = ws;
    float* w_im    = ws + 1048576;
    float* w_s1    = ws + 2097152;
    float* w_x1    = ws + 3145728;
    float* w_x2    = ws + 4194304;
    float* w_deg   = ws + 4718592;
    float* w_stat1 = ws + 4726784;
    float* w_stat2 = ws + 4726912;
    // reuse after PLI / first GCN:
    float* w_s2   = w_re;            // support2 [B,C,128] (re/im dead)
    float* w_qkv  = w_im;            // qkv [B,64,192] = 1.57M floats (spills into s1; both dead)
    float* w_ao   = w_x1;            // attn out [B,64,64] (x1 dead after support2)

    // 1. analytic signal
    analytic_kernel<<<NB * NC, NT, 0, stream>>>(eeg, w_re, w_im);
    // 2. PLI (+deg), writes wpli output
    pli_kernel<<<NB * NC, NC, 0, stream>>>(w_re, w_im, wpli, w_deg);
    // 3. GCN1 support
    gcn_support_kernel<<<NB * NC, NT, 0, stream>>>(wpli, w_deg, eeg, w_s1, NT);
    // 4. GCN1 linear
    linproj_kernel<NT, HIDN><<<NB * NC, HIDN, 0, stream>>>(w_s1, gcn1_w, gcn1_b, w_x1);
    // 5. BN1 stats + apply + ReLU
    bn_stats_kernel<<<NC, 256, 0, stream>>>(w_x1, HIDN, w_stat1);
    bn_apply_kernel<<<(NB * NC * HIDN + 255) / 256, 256, 0, stream>>>(w_x1, w_stat1, bn1_g, bn1_b, HIDN, NB * NC * HIDN);
    // 6. GCN2 support
    gcn_support_kernel<<<NB * NC, HIDN, 0, stream>>>(wpli, w_deg, w_x1, w_s2, HIDN);
    // 7. GCN2 linear
    linproj_kernel<HIDN, NE><<<NB * NC, NE, 0, stream>>>(w_s2, gcn2_w, gcn2_b, w_x2);
    // 8. BN2 stats + apply + ReLU
    bn_stats_kernel<<<NC, 256, 0, stream>>>(w_x2, NE, w_stat2);
    bn_apply_kernel<<<(NB * NC * NE + 255) / 256, 256, 0, stream>>>(w_x2, w_stat2, bn2_g, bn2_b, NE, NB * NC * NE);
    // 9. QKV projection
    qkv_kernel<<<NB, 256, 0, stream>>>(w_x2, attn_in_w, attn_in_b, w_qkv);
    // 10. attention
    attn_kernel<<<NB * NHD, NE, 0, stream>>>(w_qkv, w_ao);
    // 11. mean-pool + output projection
    outmean_kernel<<<NB, NE, 0, stream>>>(w_ao, attn_out_w, attn_out_b, feat);
}

// Round 2
// 184.516 us; speedup vs baseline: 1.7922x; 1.7922x over previous
//
#include <hip/hip_runtime.h>
#include <math.h>

#define NB 128     // batch
#define NC 64      // channels
#define NT 128     // segment length
#define HIDN 128   // hidden
#define NE 64      // attn embed
#define NHD 4      // heads
#define HD 16      // head dim

// ---------------------------------------------------------------------------
// 1. Analytic signal (Hilbert with reference's mask: bins [0,64) * 2, rest 0)
//    analytic[t] = x[t] + (1/64) * sum_{d odd} x[(t-d)&127] * (1 + i*cot(pi*d/128))
//    Stored as re/im in [b][t][c] layout for coalesced PLI reads.
//    NOTE: math kept bit-identical to round 1 (PLI sign-flip budget).
// ---------------------------------------------------------------------------
__global__ void analytic_kernel(const float* __restrict__ eeg,
                                float* __restrict__ re, float* __restrict__ im) {
    int row = blockIdx.x;            // b*NC + c
    int b = row >> 6, c = row & 63;
    int t = threadIdx.x;             // 0..127
    __shared__ float xs[NT];
    __shared__ double cotv[64];
    xs[t] = eeg[row * NT + t];
    if (t < 64) {
        double d = (double)(2 * t + 1);
        double a = 3.14159265358979323846 * d / 128.0;
        cotv[t] = cos(a) / sin(a);
    }
    __syncthreads();
    double ar = 0.0, ai = 0.0;
    #pragma unroll
    for (int m = 0; m < 64; ++m) {
        int d = 2 * m + 1;
        int s = (t - d) & 127;
        double xv = (double)xs[s];
        ar += xv;
        ai += cotv[m] * xv;
    }
    double rr = (double)xs[t] + ar * (1.0 / 64.0);
    double ii = ai * (1.0 / 64.0);
    re[b * (NT * NC) + t * NC + c] = (float)rr;
    im[b * (NT * NC) + t * NC + c] = (float)ii;
}

// ---------------------------------------------------------------------------
// 2. PLI: pli[b,i,j] = |mean_t sign(im_i*re_j - re_i*im_j)|, diag zeroed.
//    4 i-rows per 256-thread block; per-batch re/im staged in LDS chunks.
//    Integer accumulation over t in the same order as round 1 -> identical.
//    Also computes deg[b,i] (row sums) via wave shuffle (wave == one i).
// ---------------------------------------------------------------------------
__global__ void pli_kernel(const float* __restrict__ re, const float* __restrict__ im,
                           float* __restrict__ wpli, float* __restrict__ deg) {
    int blk = blockIdx.x;            // 2048: b = blk>>4, i0 = (blk&15)*4
    int b = blk >> 4;
    int i0 = (blk & 15) << 2;
    int tid = threadIdx.x;           // 256
    int di = tid >> 6, j = tid & 63;
    int i = i0 + di;
    __shared__ float sre[64][64];    // 16 KB  (t-chunk x channel)
    __shared__ float sim[64][64];    // 16 KB
    const float* reb = re + b * (NT * NC);
    const float* imb = im + b * (NT * NC);
    int acc = 0;
    #pragma unroll
    for (int tc = 0; tc < 2; ++tc) {
        for (int idx = tid; idx < 4096; idx += 256) {
            sre[idx >> 6][idx & 63] = reb[tc * 4096 + idx];
            sim[idx >> 6][idx & 63] = imb[tc * 4096 + idx];
        }
        __syncthreads();
        #pragma unroll 8
        for (int t = 0; t < 64; ++t) {
            float ri = sre[t][i];    // broadcast within wave
            float ii = sim[t][i];
            float rj = sre[t][j];    // conflict-free (lane==bank)
            float ij = sim[t][j];
            float cross = ii * rj - ri * ij;
            acc += (cross > 0.f) ? 1 : ((cross < 0.f) ? -1 : 0);
        }
        __syncthreads();
    }
    float p = fabsf((float)acc * (1.f / (float)NT));
    if (j == i) p = 0.f;
    wpli[b * (NC * NC) + i * NC + j] = p;
    float s = p;
    #pragma unroll
    for (int off = 32; off > 0; off >>= 1) s += __shfl_down(s, off);
    if (j == 0) deg[b * NC + i] = s;
}

// ---------------------------------------------------------------------------
// 3. GCN support: out[b,i,f] = sum_j adj[b,i,j]*dn[i]*dn[j] * x_eff[b,j,f]
//    BN_X: x_eff = relu(bn(x)) applied on the fly (channel = j).
// ---------------------------------------------------------------------------
template <int F, bool BN_X>
__global__ void gcn_support_kernel(const float* __restrict__ adj,
                                   const float* __restrict__ deg,
                                   const float* __restrict__ x,
                                   const float* __restrict__ mr,
                                   const float* __restrict__ g,
                                   const float* __restrict__ bb,
                                   float* __restrict__ out) {
    int row = blockIdx.x;            // b*NC + i
    int b = row >> 6, i = row & 63;
    int f = threadIdx.x;             // 0..F-1
    __shared__ float dn[NC];
    __shared__ float arow[NC];
    if (f < NC) dn[f] = (float)(1.0 / sqrt((double)deg[b * NC + f] + 1e-8));
    __syncthreads();
    if (f < NC) arow[f] = adj[b * NC * NC + i * NC + f] * dn[i] * dn[f];
    __syncthreads();
    float acc = 0.f;
    #pragma unroll 8
    for (int jj = 0; jj < NC; ++jj) {
        float v = x[b * NC * F + jj * F + f];
        if (BN_X) {
            v = (v - mr[2 * jj]) * mr[2 * jj + 1] * g[jj] + bb[jj];
            v = v > 0.f ? v : 0.f;
        }
        acc += arow[jj] * v;
    }
    out[b * NC * F + i * F + f] = acc;
}

// ---------------------------------------------------------------------------
// 4. Tiled GEMM: C[M,ldc tile] = A[M,K] @ W[N,K]^T + bias, 64x64 tiles,
//    256 threads, 4x4 micro-tile/thread. LDS transposed [k][r] with +1 pad:
//    staging writes 2-way (free), compute reads broadcast/conflict-free.
//    BN_A: apply relu(bn(.)) to A elements on load (channel = row & 63).
// ---------------------------------------------------------------------------
template <int K, bool BN_A>
__global__ void gemm64_kernel(const float* __restrict__ A,
                              const float* __restrict__ W,
                              const float* __restrict__ bias,
                              const float* __restrict__ mr,
                              const float* __restrict__ g,
                              const float* __restrict__ bb,
                              float* __restrict__ C, int ldc) {
    int m0 = blockIdx.x * 64;
    int n0 = blockIdx.y * 64;
    int tid = threadIdx.x;           // 256
    int tx = tid & 15, ty = tid >> 4;
    int r0 = ty * 4, c0 = tx * 4;
    __shared__ float AsT[64][65];    // [k][row]
    __shared__ float WsT[64][65];    // [k][col]
    float acc[4][4] = {};
    #pragma unroll
    for (int ck = 0; ck < K / 64; ++ck) {
        for (int idx = tid; idx < 4096; idx += 256) {
            int kk = idx & 63, r = idx >> 6;
            float v = A[(m0 + r) * K + ck * 64 + kk];
            if (BN_A) {
                int c = (m0 + r) & 63;
                v = (v - mr[2 * c]) * mr[2 * c + 1] * g[c] + bb[c];
                v = v > 0.f ? v : 0.f;
            }
            AsT[kk][r] = v;
            WsT[kk][r] = W[(n0 + r) * K + ck * 64 + kk];
        }
        __syncthreads();
        #pragma unroll 8
        for (int kk = 0; kk < 64; ++kk) {
            float a0 = AsT[kk][r0], a1 = AsT[kk][r0 + 1],
                  a2 = AsT[kk][r0 + 2], a3 = AsT[kk][r0 + 3];
            float w0 = WsT[kk][c0], w1 = WsT[kk][c0 + 1],
                  w2 = WsT[kk][c0 + 2], w3 = WsT[kk][c0 + 3];
            acc[0][0] += a0 * w0; acc[0][1] += a0 * w1; acc[0][2] += a0 * w2; acc[0][3] += a0 * w3;
            acc[1][0] += a1 * w0; acc[1][1] += a1 * w1; acc[1][2] += a1 * w2; acc[1][3] += a1 * w3;
            acc[2][0] += a2 * w0; acc[2][1] += a2 * w1; acc[2][2] += a2 * w2; acc[2][3] += a2 * w3;
            acc[3][0] += a3 * w0; acc[3][1] += a3 * w1; acc[3][2] += a3 * w2; acc[3][3] += a3 * w3;
        }
        __syncthreads();
    }
    float b0 = bias[n0 + c0], b1 = bias[n0 + c0 + 1],
          b2 = bias[n0 + c0 + 2], b3 = bias[n0 + c0 + 3];
    #pragma unroll
    for (int ii = 0; ii < 4; ++ii) {
        float4 v = make_float4(acc[ii][0] + b0, acc[ii][1] + b1,
                               acc[ii][2] + b2, acc[ii][3] + b3);
        *(float4*)&C[(m0 + r0 + ii) * ldc + n0 + c0] = v;
    }
}

// ---------------------------------------------------------------------------
// 5. BN stats per channel over (B,F): mean and rstd (deterministic reduction)
// ---------------------------------------------------------------------------
__global__ void bn_stats_kernel(const float* __restrict__ x, int F,
                                float* __restrict__ mr) {
    int c = blockIdx.x;
    int tid = threadIdx.x;           // 256
    double s = 0.0, s2 = 0.0;
    int total = NB * F;
    for (int idx = tid; idx < total; idx += 256) {
        int b = idx / F, f = idx - b * F;
        float v = x[b * NC * F + c * F + f];
        s += (double)v;
        s2 += (double)v * (double)v;
    }
    __shared__ double ls[256], ls2[256];
    ls[tid] = s; ls2[tid] = s2;
    __syncthreads();
    for (int off = 128; off > 0; off >>= 1) {
        if (tid < off) { ls[tid] += ls[tid + off]; ls2[tid] += ls2[tid + off]; }
        __syncthreads();
    }
    if (tid == 0) {
        double N = (double)total;
        double m = ls[0] / N;
        double var = ls2[0] / N - m * m;
        mr[2 * c] = (float)m;
        mr[2 * c + 1] = (float)(1.0 / sqrt(var + 1e-5));
    }
}

// ---------------------------------------------------------------------------
// 6. Attention per (b, head): thread = query row. scores->softmax->PV.
// ---------------------------------------------------------------------------
__global__ void attn_kernel(const float* __restrict__ qkv, float* __restrict__ ao) {
    int b = blockIdx.x >> 2, h = blockIdx.x & 3;
    int n = threadIdx.x;             // 0..63
    __shared__ float ks[NE][HD], vs[NE][HD];
    const float* base = qkv + b * (NE * 3 * NE);
    #pragma unroll
    for (int d = 0; d < HD; ++d) {
        ks[n][d] = base[n * 192 + 64 + h * HD + d];
        vs[n][d] = base[n * 192 + 128 + h * HD + d];
    }
    float q[HD];
    #pragma unroll
    for (int d = 0; d < HD; ++d) q[d] = base[n * 192 + h * HD + d];
    __syncthreads();
    float sc[NE];
    float mx = -1e30f;
    #pragma unroll
    for (int j = 0; j < NE; ++j) {
        float acc = 0.f;
        #pragma unroll
        for (int d = 0; d < HD; ++d) acc += q[d] * ks[j][d];
        acc *= 0.25f;                // 1/sqrt(16)
        sc[j] = acc;
        mx = fmaxf(mx, acc);
    }
    float sum = 0.f;
    #pragma unroll
    for (int j = 0; j < NE; ++j) { sc[j] = expf(sc[j] - mx); sum += sc[j]; }
    float inv = 1.f / sum;
    float o[HD];
    #pragma unroll
    for (int d = 0; d < HD; ++d) o[d] = 0.f;
    #pragma unroll
    for (int j = 0; j < NE; ++j) {
        float p = sc[j] * inv;
        #pragma unroll
        for (int d = 0; d < HD; ++d) o[d] += p * vs[j][d];
    }
    #pragma unroll
    for (int d = 0; d < HD; ++d) ao[b * 4096 + n * 64 + h * HD + d] = o[d];
}

// ---------------------------------------------------------------------------
// 7. Mean over nodes, then output projection
// ---------------------------------------------------------------------------
__global__ void outmean_kernel(const float* __restrict__ ao, const float* __restrict__ W,
                               const float* __restrict__ bias, float* __restrict__ feat) {
    int b = blockIdx.x;
    int tid = threadIdx.x;           // 0..63
    float s = 0.f;
    for (int n = 0; n < NE; ++n) s += ao[b * 4096 + n * 64 + tid];
    __shared__ float mo[NE];
    mo[tid] = s * (1.f / 64.f);
    __syncthreads();
    float acc = bias[tid];
    #pragma unroll
    for (int d = 0; d < NE; ++d) acc += mo[d] * W[tid * NE + d];
    feat[b * NE + tid] = acc;
}

// ---------------------------------------------------------------------------
extern "C" void kernel_launch(void* const* d_in, const int* in_sizes, int n_in,
                              void* d_out, int out_size, void* d_ws, size_t ws_size,
                              hipStream_t stream) {
    const float* eeg      = (const float*)d_in[0];
    const float* gcn1_w   = (const float*)d_in[1];
    const float* gcn1_b   = (const float*)d_in[2];
    const float* gcn2_w   = (const float*)d_in[3];
    const float* gcn2_b   = (const float*)d_in[4];
    const float* bn1_g    = (const float*)d_in[5];
    const float* bn1_b    = (const float*)d_in[6];
    const float* bn2_g    = (const float*)d_in[7];
    const float* bn2_b    = (const float*)d_in[8];
    const float* attn_in_w  = (const float*)d_in[9];
    const float* attn_in_b  = (const float*)d_in[10];
    const float* attn_out_w = (const float*)d_in[11];
    const float* attn_out_b = (const float*)d_in[12];

    float* out  = (float*)d_out;
    float* feat = out;               // [B, E] = 8192 floats
    float* wpli = out + NB * NE;     // [B, C, C] = 524288 floats

    float* ws = (float*)d_ws;
    float* w_re    = ws;             // [1M]  analytic re -> later s2
    float* w_im    = ws + 1048576;   // [1M]  analytic im -> later qkv (spills into s1)
    float* w_s1    = ws + 2097152;   // [1M]  support1
    float* w_x1    = ws + 3145728;   // [1M]  x1 -> later ao
    float* w_x2    = ws + 4194304;   // [512K] x2
    float* w_deg   = ws + 4718592;   // [8K]
    float* w_stat1 = ws + 4726784;   // [128]
    float* w_stat2 = ws + 4726912;   // [128]
    float* w_s2   = w_re;
    float* w_qkv  = w_im;            // [B,64,192] = 1.57M floats
    float* w_ao   = w_x1;

    // 1. analytic signal
    analytic_kernel<<<NB * NC, NT, 0, stream>>>(eeg, w_re, w_im);
    // 2. PLI (+deg), writes wpli output
    pli_kernel<<<NB * NC / 4, 256, 0, stream>>>(w_re, w_im, wpli, w_deg);
    // 3. GCN1 support
    gcn_support_kernel<NT, false><<<NB * NC, NT, 0, stream>>>(
        wpli, w_deg, eeg, nullptr, nullptr, nullptr, w_s1);
    // 4. GCN1 linear (tiled GEMM)
    gemm64_kernel<NT, false><<<dim3(NB * NC / 64, HIDN / 64), 256, 0, stream>>>(
        w_s1, gcn1_w, gcn1_b, nullptr, nullptr, nullptr, w_x1, HIDN);
    // 5. BN1 stats
    bn_stats_kernel<<<NC, 256, 0, stream>>>(w_x1, HIDN, w_stat1);
    // 6. GCN2 support (BN1+ReLU fused into x read)
    gcn_support_kernel<HIDN, true><<<NB * NC, HIDN, 0, stream>>>(
        wpli, w_deg, w_x1, w_stat1, bn1_g, bn1_b, w_s2);
    // 7. GCN2 linear
    gemm64_kernel<HIDN, false><<<dim3(NB * NC / 64, NE / 64), 256, 0, stream>>>(
        w_s2, gcn2_w, gcn2_b, nullptr, nullptr, nullptr, w_x2, NE);
    // 8. BN2 stats
    bn_stats_kernel<<<NC, 256, 0, stream>>>(w_x2, NE, w_stat2);
    // 9. QKV projection (BN2+ReLU fused into A read)
    gemm64_kernel<NE, true><<<dim3(NB * NC / 64, 3 * NE / 64), 256, 0, stream>>>(
        w_x2, attn_in_w, attn_in_b, w_stat2, bn2_g, bn2_b, w_qkv, 3 * NE);
    // 10. attention
    attn_kernel<<<NB * NHD, NE, 0, stream>>>(w_qkv, w_ao);
    // 11. mean-pool + output projection
    outmean_kernel<<<NB, NE, 0, stream>>>(w_ao, attn_out_w, attn_out_b, feat);
}

// Round 3
// 169.986 us; speedup vs baseline: 1.9454x; 1.0855x over previous
//
#include <hip/hip_runtime.h>
#include <math.h>

#define NB 128     // batch
#define NC 64      // channels
#define NT 128     // segment length
#define HIDN 128   // hidden
#define NE 64      // attn embed
#define NHD 4      // heads
#define HD 16      // head dim

// ---------------------------------------------------------------------------
// 1. Analytic signal (Hilbert, reference mask): bit-identical to round 1/2.
// ---------------------------------------------------------------------------
__global__ void analytic_kernel(const float* __restrict__ eeg,
                                float* __restrict__ re, float* __restrict__ im) {
    int row = blockIdx.x;            // b*NC + c
    int b = row >> 6, c = row & 63;
    int t = threadIdx.x;             // 0..127
    __shared__ float xs[NT];
    __shared__ double cotv[64];
    xs[t] = eeg[row * NT + t];
    if (t < 64) {
        double d = (double)(2 * t + 1);
        double a = 3.14159265358979323846 * d / 128.0;
        cotv[t] = cos(a) / sin(a);
    }
    __syncthreads();
    double ar = 0.0, ai = 0.0;
    #pragma unroll
    for (int m = 0; m < 64; ++m) {
        int d = 2 * m + 1;
        int s = (t - d) & 127;
        double xv = (double)xs[s];
        ar += xv;
        ai += cotv[m] * xv;
    }
    double rr = (double)xs[t] + ar * (1.0 / 64.0);
    double ii = ai * (1.0 / 64.0);
    re[b * (NT * NC) + t * NC + c] = (float)rr;
    im[b * (NT * NC) + t * NC + c] = (float)ii;
}

// ---------------------------------------------------------------------------
// 2. PLI (+deg row sums). Bit-identical accumulation to round 2.
// ---------------------------------------------------------------------------
__global__ void pli_kernel(const float* __restrict__ re, const float* __restrict__ im,
                           float* __restrict__ wpli, float* __restrict__ deg) {
    int blk = blockIdx.x;            // 2048
    int b = blk >> 4;
    int i0 = (blk & 15) << 2;
    int tid = threadIdx.x;           // 256
    int di = tid >> 6, j = tid & 63;
    int i = i0 + di;
    __shared__ float sre[64][64];
    __shared__ float sim[64][64];
    const float* reb = re + b * (NT * NC);
    const float* imb = im + b * (NT * NC);
    int acc = 0;
    #pragma unroll
    for (int tc = 0; tc < 2; ++tc) {
        for (int idx = tid; idx < 4096; idx += 256) {
            sre[idx >> 6][idx & 63] = reb[tc * 4096 + idx];
            sim[idx >> 6][idx & 63] = imb[tc * 4096 + idx];
        }
        __syncthreads();
        #pragma unroll 8
        for (int t = 0; t < 64; ++t) {
            float ri = sre[t][i];
            float ii = sim[t][i];
            float rj = sre[t][j];
            float ij = sim[t][j];
            float cross = ii * rj - ri * ij;
            acc += (cross > 0.f) ? 1 : ((cross < 0.f) ? -1 : 0);
        }
        __syncthreads();
    }
    float p = fabsf((float)acc * (1.f / (float)NT));
    if (j == i) p = 0.f;
    wpli[b * (NC * NC) + i * NC + j] = p;
    float s = p;
    #pragma unroll
    for (int off = 32; off > 0; off >>= 1) s += __shfl_down(s, off);
    if (j == 0) deg[b * NC + i] = s;
}

// ---------------------------------------------------------------------------
// 3. GCN support v2: 4 i-rows per block, x[b] staged in LDS (BN fused).
//    Block: 4*F threads. Grid: NB*NC/4.
// ---------------------------------------------------------------------------
template <int F, bool BN_X>
__global__ void gcn_support_v2(const float* __restrict__ adj,
                               const float* __restrict__ deg,
                               const float* __restrict__ x,
                               const float* __restrict__ mr,
                               const float* __restrict__ g,
                               const float* __restrict__ bb,
                               float* __restrict__ out) {
    int b = blockIdx.x >> 4;
    int i0 = (blockIdx.x & 15) << 2;
    int tid = threadIdx.x;           // 4*F
    int di = tid / F;                // 0..3
    int f = tid % F;
    int i = i0 + di;
    __shared__ float xs[NC][F + 1];
    __shared__ float arow[4][NC];
    __shared__ float dn[NC];
    if (tid < NC) dn[tid] = (float)(1.0 / sqrt((double)deg[b * NC + tid] + 1e-8));
    __syncthreads();
    if (tid < 4 * NC) {
        int r = tid >> 6, j = tid & 63;
        arow[r][j] = adj[b * NC * NC + (i0 + r) * NC + j] * dn[i0 + r] * dn[j];
    }
    // stage x[b] as float4 (coalesced); BN channel = row j
    for (int idx4 = tid; idx4 < NC * F / 4; idx4 += 4 * F) {
        int idx = idx4 * 4;
        int j = idx / F, ff = idx % F;
        float4 v = *(const float4*)&x[b * NC * F + idx];
        if (BN_X) {
            float m = mr[2 * j], r = mr[2 * j + 1], gg = g[j], bv = bb[j];
            v.x = (v.x - m) * r * gg + bv; v.x = v.x > 0.f ? v.x : 0.f;
            v.y = (v.y - m) * r * gg + bv; v.y = v.y > 0.f ? v.y : 0.f;
            v.z = (v.z - m) * r * gg + bv; v.z = v.z > 0.f ? v.z : 0.f;
            v.w = (v.w - m) * r * gg + bv; v.w = v.w > 0.f ? v.w : 0.f;
        }
        xs[j][ff] = v.x; xs[j][ff + 1] = v.y; xs[j][ff + 2] = v.z; xs[j][ff + 3] = v.w;
    }
    __syncthreads();
    float acc = 0.f;
    #pragma unroll 16
    for (int jj = 0; jj < NC; ++jj)
        acc += arow[di][jj] * xs[jj][f];     // arow broadcast, xs conflict-free
    out[b * NC * F + i * F + f] = acc;
}

// ---------------------------------------------------------------------------
// 4. Tiled GEMM (unchanged from round 2): C = A @ W^T + bias, 64x64 tiles.
// ---------------------------------------------------------------------------
template <int K, bool BN_A>
__global__ void gemm64_kernel(const float* __restrict__ A,
                              const float* __restrict__ W,
                              const float* __restrict__ bias,
                              const float* __restrict__ mr,
                              const float* __restrict__ g,
                              const float* __restrict__ bb,
                              float* __restrict__ C, int ldc) {
    int m0 = blockIdx.x * 64;
    int n0 = blockIdx.y * 64;
    int tid = threadIdx.x;           // 256
    int tx = tid & 15, ty = tid >> 4;
    int r0 = ty * 4, c0 = tx * 4;
    __shared__ float AsT[64][65];
    __shared__ float WsT[64][65];
    float acc[4][4] = {};
    #pragma unroll
    for (int ck = 0; ck < K / 64; ++ck) {
        for (int idx = tid; idx < 4096; idx += 256) {
            int kk = idx & 63, r = idx >> 6;
            float v = A[(m0 + r) * K + ck * 64 + kk];
            if (BN_A) {
                int c = (m0 + r) & 63;
                v = (v - mr[2 * c]) * mr[2 * c + 1] * g[c] + bb[c];
                v = v > 0.f ? v : 0.f;
            }
            AsT[kk][r] = v;
            WsT[kk][r] = W[(n0 + r) * K + ck * 64 + kk];
        }
        __syncthreads();
        #pragma unroll 8
        for (int kk = 0; kk < 64; ++kk) {
            float a0 = AsT[kk][r0], a1 = AsT[kk][r0 + 1],
                  a2 = AsT[kk][r0 + 2], a3 = AsT[kk][r0 + 3];
            float w0 = WsT[kk][c0], w1 = WsT[kk][c0 + 1],
                  w2 = WsT[kk][c0 + 2], w3 = WsT[kk][c0 + 3];
            acc[0][0] += a0 * w0; acc[0][1] += a0 * w1; acc[0][2] += a0 * w2; acc[0][3] += a0 * w3;
            acc[1][0] += a1 * w0; acc[1][1] += a1 * w1; acc[1][2] += a1 * w2; acc[1][3] += a1 * w3;
            acc[2][0] += a2 * w0; acc[2][1] += a2 * w1; acc[2][2] += a2 * w2; acc[2][3] += a2 * w3;
            acc[3][0] += a3 * w0; acc[3][1] += a3 * w1; acc[3][2] += a3 * w2; acc[3][3] += a3 * w3;
        }
        __syncthreads();
    }
    float b0 = bias[n0 + c0], b1 = bias[n0 + c0 + 1],
          b2 = bias[n0 + c0 + 2], b3 = bias[n0 + c0 + 3];
    #pragma unroll
    for (int ii = 0; ii < 4; ++ii) {
        float4 v = make_float4(acc[ii][0] + b0, acc[ii][1] + b1,
                               acc[ii][2] + b2, acc[ii][3] + b3);
        *(float4*)&C[(m0 + r0 + ii) * ldc + n0 + c0] = v;
    }
}

// ---------------------------------------------------------------------------
// 5. BN stats per channel, 1024 threads (deterministic tree reduction).
// ---------------------------------------------------------------------------
__global__ void bn_stats_kernel(const float* __restrict__ x, int F,
                                float* __restrict__ mr) {
    int c = blockIdx.x;
    int tid = threadIdx.x;           // 1024
    double s = 0.0, s2 = 0.0;
    int total = NB * F;
    for (int idx = tid; idx < total; idx += 1024) {
        int b = idx / F, f = idx - b * F;
        float v = x[b * NC * F + c * F + f];
        s += (double)v;
        s2 += (double)v * (double)v;
    }
    __shared__ double ls[1024], ls2[1024];
    ls[tid] = s; ls2[tid] = s2;
    __syncthreads();
    for (int off = 512; off > 0; off >>= 1) {
        if (tid < off) { ls[tid] += ls[tid + off]; ls2[tid] += ls2[tid + off]; }
        __syncthreads();
    }
    if (tid == 0) {
        double N = (double)total;
        double m = ls[0] / N;
        double var = ls2[0] / N - m * m;
        mr[2 * c] = (float)m;
        mr[2 * c + 1] = (float)(1.0 / sqrt(var + 1e-5));
    }
}

// ---------------------------------------------------------------------------
// 6. Fused BN2+ReLU -> QKV -> 4-head attention -> mean-pool -> out-proj.
//    One block per batch, 256 threads = (og/head, n).
// ---------------------------------------------------------------------------
__global__ __launch_bounds__(256) void attn_fused(
        const float* __restrict__ x2, const float* __restrict__ mr,
        const float* __restrict__ g, const float* __restrict__ bb,
        const float* __restrict__ Win, const float* __restrict__ bin,
        const float* __restrict__ Wout, const float* __restrict__ bout,
        float* __restrict__ feat) {
    int b = blockIdx.x;
    int tid = threadIdx.x;
    int n = tid & 63, og = tid >> 6;       // og == wave id (uniform per wave)
    __shared__ float qs[64][65], ks[64][65], vs[64][65];
    __shared__ float mo[64];
    // --- load x row n (BN2 + ReLU), into registers ---
    const float* xrow = x2 + b * 4096 + n * 64;
    float xr[64];
    {
        float m = mr[2 * n], r = mr[2 * n + 1], gg = g[n], bv = bb[n];
        #pragma unroll
        for (int q4 = 0; q4 < 16; ++q4) {
            float4 v = ((const float4*)xrow)[q4];
            float a0 = (v.x - m) * r * gg + bv;
            float a1 = (v.y - m) * r * gg + bv;
            float a2 = (v.z - m) * r * gg + bv;
            float a3 = (v.w - m) * r * gg + bv;
            xr[q4 * 4 + 0] = a0 > 0.f ? a0 : 0.f;
            xr[q4 * 4 + 1] = a1 > 0.f ? a1 : 0.f;
            xr[q4 * 4 + 2] = a2 > 0.f ? a2 : 0.f;
            xr[q4 * 4 + 3] = a3 > 0.f ? a3 : 0.f;
        }
    }
    // --- QKV projection: o = og*48+u; W reads wave-uniform (scalar path) ---
    for (int u = 0; u < 48; ++u) {
        int o = og * 48 + u;
        float acc = bin[o];
        const float* wr = Win + o * 64;
        #pragma unroll
        for (int d = 0; d < 64; ++d) acc += xr[d] * wr[d];
        if (o < 64)       qs[n][o] = acc;
        else if (o < 128) ks[n][o - 64] = acc;
        else              vs[n][o - 128] = acc;
    }
    __syncthreads();
    // --- attention: thread = (head og, query n) ---
    int e0 = og * HD;
    float q[HD];
    #pragma unroll
    for (int d = 0; d < HD; ++d) q[d] = qs[n][e0 + d];
    float sc[NE];
    float mx = -1e30f;
    #pragma unroll 8
    for (int j = 0; j < NE; ++j) {
        float acc = 0.f;
        #pragma unroll
        for (int d = 0; d < HD; ++d) acc += q[d] * ks[j][e0 + d];
        acc *= 0.25f;
        sc[j] = acc;
        mx = fmaxf(mx, acc);
    }
    float sum = 0.f;
    #pragma unroll 8
    for (int j = 0; j < NE; ++j) { sc[j] = expf(sc[j] - mx); sum += sc[j]; }
    float inv = 1.f / sum;
    float o[HD];
    #pragma unroll
    for (int d = 0; d < HD; ++d) o[d] = 0.f;
    #pragma unroll 8
    for (int j = 0; j < NE; ++j) {
        float p = sc[j] * inv;
        #pragma unroll
        for (int d = 0; d < HD; ++d) o[d] += p * vs[j][e0 + d];
    }
    __syncthreads();                 // all reads of qs done before overwrite
    #pragma unroll
    for (int d = 0; d < HD; ++d) qs[n][e0 + d] = o[d];   // qs now holds ao
    __syncthreads();
    // --- mean over nodes + output projection ---
    if (tid < 64) {
        float s = 0.f;
        #pragma unroll 8
        for (int n2 = 0; n2 < 64; ++n2) s += qs[n2][tid];
        mo[tid] = s * (1.f / 64.f);
    }
    __syncthreads();
    if (tid < 64) {
        float acc = bout[tid];
        const float* wr = Wout + tid * 64;
        #pragma unroll 8
        for (int d = 0; d < 64; ++d) acc += mo[d] * wr[d];
        feat[b * NE + tid] = acc;
    }
}

// ---------------------------------------------------------------------------
extern "C" void kernel_launch(void* const* d_in, const int* in_sizes, int n_in,
                              void* d_out, int out_size, void* d_ws, size_t ws_size,
                              hipStream_t stream) {
    const float* eeg      = (const float*)d_in[0];
    const float* gcn1_w   = (const float*)d_in[1];
    const float* gcn1_b   = (const float*)d_in[2];
    const float* gcn2_w   = (const float*)d_in[3];
    const float* gcn2_b   = (const float*)d_in[4];
    const float* bn1_g    = (const float*)d_in[5];
    const float* bn1_b    = (const float*)d_in[6];
    const float* bn2_g    = (const float*)d_in[7];
    const float* bn2_b    = (const float*)d_in[8];
    const float* attn_in_w  = (const float*)d_in[9];
    const float* attn_in_b  = (const float*)d_in[10];
    const float* attn_out_w = (const float*)d_in[11];
    const float* attn_out_b = (const float*)d_in[12];

    float* out  = (float*)d_out;
    float* feat = out;               // [B, E]
    float* wpli = out + NB * NE;     // [B, C, C]

    float* ws = (float*)d_ws;
    float* w_re    = ws;             // [1M] -> reused as s2
    float* w_im    = ws + 1048576;   // [1M]
    float* w_s1    = ws + 2097152;   // [1M]
    float* w_x1    = ws + 3145728;   // [1M]
    float* w_x2    = ws + 4194304;   // [512K]
    float* w_deg   = ws + 4718592;
    float* w_stat1 = ws + 4726784;
    float* w_stat2 = ws + 4726912;
    float* w_s2    = w_re;

    // 1. analytic signal
    analytic_kernel<<<NB * NC, NT, 0, stream>>>(eeg, w_re, w_im);
    // 2. PLI (+deg)
    pli_kernel<<<NB * NC / 4, 256, 0, stream>>>(w_re, w_im, wpli, w_deg);
    // 3. GCN1 support (LDS-staged)
    gcn_support_v2<NT, false><<<NB * NC / 4, 4 * NT, 0, stream>>>(
        wpli, w_deg, eeg, nullptr, nullptr, nullptr, w_s1);
    // 4. GCN1 linear
    gemm64_kernel<NT, false><<<dim3(NB * NC / 64, HIDN / 64), 256, 0, stream>>>(
        w_s1, gcn1_w, gcn1_b, nullptr, nullptr, nullptr, w_x1, HIDN);
    // 5. BN1 stats
    bn_stats_kernel<<<NC, 1024, 0, stream>>>(w_x1, HIDN, w_stat1);
    // 6. GCN2 support (BN1+ReLU fused at stage)
    gcn_support_v2<HIDN, true><<<NB * NC / 4, 4 * HIDN, 0, stream>>>(
        wpli, w_deg, w_x1, w_stat1, bn1_g, bn1_b, w_s2);
    // 7. GCN2 linear
    gemm64_kernel<HIDN, false><<<dim3(NB * NC / 64, NE / 64), 256, 0, stream>>>(
        w_s2, gcn2_w, gcn2_b, nullptr, nullptr, nullptr, w_x2, NE);
    // 8. BN2 stats
    bn_stats_kernel<<<NC, 1024, 0, stream>>>(w_x2, NE, w_stat2);
    // 9. fused BN2 -> QKV -> attention -> pool -> proj
    attn_fused<<<NB, 256, 0, stream>>>(w_x2, w_stat2, bn2_g, bn2_b,
                                       attn_in_w, attn_in_b,
                                       attn_out_w, attn_out_b, feat);
}